// Round 3
// baseline (1858.603 us; speedup 1.0000x reference)
//
#include <hip/hip_runtime.h>

// ---------------------------------------------------------------------------
// SublayerConnection: MHA + residual/LN + FF + residual/LN
// B=4 S=2048 D=1024 H=16 Dk=64 Dff=4096.
// Dtype-agnostic: device-side detector decides bf16 vs fp32 inputs; all
// input loads / output stores branch uniformly on the flag. Host-side
// ws_size branch picks flat (96MiB) vs per-batch-chunked (40MiB) schedule.
// fp32 accumulation everywhere; internal tensors bf16.
// ---------------------------------------------------------------------------

#define DM   1024
#define DFF  4096
#define SEQ  2048

typedef unsigned short u16;
typedef short          sx8  __attribute__((ext_vector_type(8)));
typedef unsigned short ushx8 __attribute__((ext_vector_type(8)));
typedef unsigned short ushx4 __attribute__((ext_vector_type(4)));
typedef float          fx4  __attribute__((ext_vector_type(4)));

__device__ __forceinline__ float b2f(u16 u) {
  union { unsigned int i; float f; } v; v.i = ((unsigned int)u) << 16; return v.f;
}
__device__ __forceinline__ u16 f2b(float f) {
  union { float f; unsigned int i; } v; v.f = f;
  unsigned int r = v.i + 0x7fffu + ((v.i >> 16) & 1u);
  return (u16)(r >> 16);
}

// 8 consecutive logical elements from a maybe-fp32 tensor, as bf16 bits.
__device__ __forceinline__ ushx8 ld8(const void* p, long idx, bool f32) {
  if (f32) {
    const float* s = (const float*)p + idx;
    fx4 a = *(const fx4*)s, b = *(const fx4*)(s + 4);
    ushx8 r;
    r[0] = f2b(a[0]); r[1] = f2b(a[1]); r[2] = f2b(a[2]); r[3] = f2b(a[3]);
    r[4] = f2b(b[0]); r[5] = f2b(b[1]); r[6] = f2b(b[2]); r[7] = f2b(b[3]);
    return r;
  }
  return *(const ushx8*)((const u16*)p + idx);
}
// 4 consecutive logical elements as fp32 values.
__device__ __forceinline__ void ld4f(const void* p, long idx, bool f32, float* o) {
  if (f32) {
    fx4 a = *(const fx4*)((const float*)p + idx);
    o[0] = a[0]; o[1] = a[1]; o[2] = a[2]; o[3] = a[3];
  } else {
    ushx4 a = *(const ushx4*)((const u16*)p + idx);
    o[0] = b2f(a[0]); o[1] = b2f(a[1]); o[2] = b2f(a[2]); o[3] = b2f(a[3]);
  }
}

// ---------------------------------------------------------------------------
// Dtype detector: even-indexed u16s of a bf16 N(0,1) tensor are all plausible
// bf16 values; for fp32 data they are mantissa-low garbage. flags[0]=isf32,
// flags[1]=0 (constant for always-bf16 operands).
// ---------------------------------------------------------------------------
__global__ void detect_kernel(const void* q, int* flags) {
  int lane = threadIdx.x;
  u16 v = ((const u16*)q)[lane << 1];
  int e = (v >> 7) & 0xff;
  int pl = (e >= 0x60 && e <= 0x8c) ? 1 : 0;
  unsigned long long m = __ballot(pl);
  if (lane == 0) { flags[0] = (__popcll(m) >= 40) ? 0 : 1; flags[1] = 0; }
}

// ---------------------------------------------------------------------------
// NT GEMM: C[M,N] = A[M,K] @ B[N,K]^T (+bias) (+relu). 128x128 tile, BK=64,
// XOR-swizzled LDS, 16x16x32 bf16 MFMA. A/B/bias dtype via runtime flags.
// ---------------------------------------------------------------------------
template<bool RELU, bool BIAS>
__global__ __launch_bounds__(256)
void gemm_nt(const void* __restrict__ A, long aoff, const void* __restrict__ Bm,
             const void* __restrict__ bias, u16* __restrict__ C,
             int M, int N, int K,
             const int* af_p, const int* bf_p, const int* biasf_p) {
  __shared__ __align__(16) u16 sA[128 * 64];
  __shared__ __align__(16) u16 sB[128 * 64];
  const bool af = (*af_p != 0), bfl = (*bf_p != 0), biasf = (*biasf_p != 0);
  const int t = threadIdx.x;
  const int lane = t & 63, w = t >> 6;
  const int lm = lane & 15, lg = lane >> 4;
  const int ntil = N >> 7;
  const int m0 = (blockIdx.x / ntil) << 7;
  const int n0 = (blockIdx.x % ntil) << 7;
  const int wm = (w & 1) << 6, wn = (w >> 1) << 6;

  fx4 acc[4][4];
#pragma unroll
  for (int i = 0; i < 4; ++i)
#pragma unroll
    for (int j = 0; j < 4; ++j) acc[i][j] = (fx4){0.f, 0.f, 0.f, 0.f};

  for (int kt = 0; kt < K; kt += 64) {
    __syncthreads();
#pragma unroll
    for (int it = 0; it < 4; ++it) {
      int ci = (it << 8) + t;
      int r = ci >> 3, cs = (ci & 7) ^ (r & 7);
      ushx8 va = ld8(A, aoff + (long)(m0 + r) * K + kt + (cs << 3), af);
      *(ushx8*)&sA[ci << 3] = va;
      ushx8 vb = ld8(Bm, (long)(n0 + r) * K + kt + (cs << 3), bfl);
      *(ushx8*)&sB[ci << 3] = vb;
    }
    __syncthreads();
#pragma unroll
    for (int s = 0; s < 2; ++s) {
      const int g = (s << 2) + lg;
      sx8 afr[4], bfr[4];
#pragma unroll
      for (int i = 0; i < 4; ++i) {
        int ra = wm + (i << 4) + lm;
        afr[i] = *(const sx8*)&sA[ra * 64 + ((g ^ (ra & 7)) << 3)];
        int rb = wn + (i << 4) + lm;
        bfr[i] = *(const sx8*)&sB[rb * 64 + ((g ^ (rb & 7)) << 3)];
      }
#pragma unroll
      for (int i = 0; i < 4; ++i)
#pragma unroll
        for (int j = 0; j < 4; ++j)
          acc[i][j] = __builtin_amdgcn_mfma_f32_16x16x32_bf16(afr[i], bfr[j], acc[i][j], 0, 0, 0);
    }
  }

#pragma unroll
  for (int j = 0; j < 4; ++j) {
    const int col = n0 + wn + (j << 4) + lm;
    float bv = 0.f;
    if (BIAS) bv = biasf ? ((const float*)bias)[col] : b2f(((const u16*)bias)[col]);
#pragma unroll
    for (int i = 0; i < 4; ++i) {
      const int row0 = m0 + wm + (i << 4) + (lg << 2);
#pragma unroll
      for (int r = 0; r < 4; ++r) {
        float v = acc[i][j][r] + bv;
        if (RELU) v = fmaxf(v, 0.f);
        C[(size_t)(row0 + r) * N + col] = f2b(v);
      }
    }
  }
}

// ---------------------------------------------------------------------------
// transpose: out[c*R + r] = in[r*C + c] (bf16 out; in dtype via flag).
// ---------------------------------------------------------------------------
__global__ __launch_bounds__(256)
void transpose_any(const void* __restrict__ in, u16* __restrict__ out,
                   int R, int C, const int* f_p) {
  __shared__ u16 tile[64][68];
  const bool f = (*f_p != 0);
  const int r0 = blockIdx.y << 6, c0 = blockIdx.x << 6;
  const int t = threadIdx.x;
#pragma unroll
  for (int it = 0; it < 4; ++it) {
    int j = (it << 8) + t;
    int rr = j >> 4, cc4 = (j & 15) << 2;
    float v[4];
    ld4f(in, (long)(r0 + rr) * C + c0 + cc4, f, v);
#pragma unroll
    for (int q = 0; q < 4; ++q) tile[rr][cc4 + q] = f2b(v[q]);
  }
  __syncthreads();
#pragma unroll
  for (int it = 0; it < 4; ++it) {
    int j = (it << 8) + t;
    int cc = j >> 4, rr4 = (j & 15) << 2;
    ushx4 v;
    v[0] = tile[rr4 + 0][cc]; v[1] = tile[rr4 + 1][cc];
    v[2] = tile[rr4 + 2][cc]; v[3] = tile[rr4 + 3][cc];
    *(ushx4*)&out[(size_t)(c0 + cc) * R + r0 + rr4] = v;
  }
}

// ---------------------------------------------------------------------------
// Flash attention over ONE batch (pointers pre-offset; 2048 local rows).
// Block = (h, 64 q rows); grid 16*32=512. 4 waves x 16 q rows.
// ---------------------------------------------------------------------------
__global__ __launch_bounds__(256)
void attn_kernel(const u16* __restrict__ qp, const u16* __restrict__ kp,
                 const u16* __restrict__ vp, const int* __restrict__ mask,
                 u16* __restrict__ ctx) {
  __shared__ __align__(16) u16 sQ[64 * 64];
  __shared__ __align__(16) u16 sK[128 * 64];
  __shared__ __align__(16) u16 sVt[64 * 136];
  __shared__ __align__(16) u16 sP[4][16 * 136];

  const int id = blockIdx.x;
  const int q0 = (id & 31) << 6;
  const int h  = id >> 5;
  const int t = threadIdx.x, lane = t & 63, w = t >> 6;
  const int hoff = h << 6;
  const int lm = lane & 15, lg = lane >> 4;

#pragma unroll
  for (int it = 0; it < 2; ++it) {
    int ci = (it << 8) + t;
    int r = ci >> 3, cs = (ci & 7) ^ (r & 7);
    ushx8 v = *(const ushx8*)&qp[((size_t)(q0 + r) << 10) + hoff + (cs << 3)];
    *(ushx8*)&sQ[ci << 3] = v;
  }

  fx4 o[4];
  float m_prev[4], lsum[4];
#pragma unroll
  for (int i = 0; i < 4; ++i) { o[i] = (fx4){0.f, 0.f, 0.f, 0.f}; m_prev[i] = -1e30f; lsum[i] = 0.f; }

  for (int kt = 0; kt < 16; ++kt) {
    const int k0 = kt << 7;
    __syncthreads();
#pragma unroll
    for (int it = 0; it < 4; ++it) {
      int ci = (it << 8) + t;
      int r = ci >> 3, cs = (ci & 7) ^ (r & 7);
      ushx8 v = *(const ushx8*)&kp[((size_t)(k0 + r) << 10) + hoff + (cs << 3)];
      *(ushx8*)&sK[ci << 3] = v;
    }
    {
      const int key = t >> 1;
#pragma unroll
      for (int it = 0; it < 4; ++it) {
        int dc = (t & 1) + (it << 1);
        ushx8 vv = *(const ushx8*)&vp[((size_t)(k0 + key) << 10) + hoff + (dc << 3)];
#pragma unroll
        for (int j = 0; j < 8; ++j)
          sVt[((dc << 3) + j) * 136 + key] = vv[j];
      }
    }
    __syncthreads();

    fx4 sc[8];
#pragma unroll
    for (int nt = 0; nt < 8; ++nt) sc[nt] = (fx4){0.f, 0.f, 0.f, 0.f};
#pragma unroll
    for (int s = 0; s < 2; ++s) {
      const int g = (s << 2) + lg;
      const int rowq = (w << 4) + lm;
      sx8 aq = *(const sx8*)&sQ[rowq * 64 + ((g ^ (rowq & 7)) << 3)];
#pragma unroll
      for (int nt = 0; nt < 8; ++nt) {
        int rk = (nt << 4) + lm;
        sx8 bk = *(const sx8*)&sK[rk * 64 + ((g ^ (rk & 7)) << 3)];
        sc[nt] = __builtin_amdgcn_mfma_f32_16x16x32_bf16(aq, bk, sc[nt], 0, 0, 0);
      }
    }

    float pmat[8][4];
    float tmax[4] = {-1e30f, -1e30f, -1e30f, -1e30f};
#pragma unroll
    for (int nt = 0; nt < 8; ++nt) {
      const int col = k0 + (nt << 4) + lm;
#pragma unroll
      for (int r = 0; r < 4; ++r) {
        const int rowg = q0 + (w << 4) + (lg << 2) + r;
        float v = sc[nt][r] * 0.125f;
        if (mask[((size_t)rowg << 11) + col] == 0) v = -1e9f;
        pmat[nt][r] = v;
        tmax[r] = fmaxf(tmax[r], v);
      }
    }
#pragma unroll
    for (int r = 0; r < 4; ++r)
#pragma unroll
      for (int off = 1; off < 16; off <<= 1)
        tmax[r] = fmaxf(tmax[r], __shfl_xor(tmax[r], off));

    float alpha[4], rsum[4] = {0.f, 0.f, 0.f, 0.f};
#pragma unroll
    for (int r = 0; r < 4; ++r) {
      float mn = fmaxf(m_prev[r], tmax[r]);
      alpha[r] = __expf(m_prev[r] - mn);
      m_prev[r] = mn;
    }
#pragma unroll
    for (int nt = 0; nt < 8; ++nt)
#pragma unroll
      for (int r = 0; r < 4; ++r) {
        float pv = __expf(pmat[nt][r] - m_prev[r]);
        pmat[nt][r] = pv;
        rsum[r] += pv;
      }
#pragma unroll
    for (int r = 0; r < 4; ++r) {
#pragma unroll
      for (int off = 1; off < 16; off <<= 1)
        rsum[r] += __shfl_xor(rsum[r], off);
      lsum[r] = lsum[r] * alpha[r] + rsum[r];
    }
#pragma unroll
    for (int ot = 0; ot < 4; ++ot)
#pragma unroll
      for (int r = 0; r < 4; ++r)
        o[ot][r] *= alpha[r];

    u16* pw = &sP[w][0];
#pragma unroll
    for (int nt = 0; nt < 8; ++nt)
#pragma unroll
      for (int r = 0; r < 4; ++r)
        pw[((lg << 2) + r) * 136 + (nt << 4) + lm] = f2b(pmat[nt][r]);

#pragma unroll
    for (int ks = 0; ks < 4; ++ks) {
      sx8 ap = *(const sx8*)&pw[lm * 136 + (ks << 5) + (lg << 3)];
#pragma unroll
      for (int ot = 0; ot < 4; ++ot) {
        int d = (ot << 4) + lm;
        sx8 bv = *(const sx8*)&sVt[d * 136 + (ks << 5) + (lg << 3)];
        o[ot] = __builtin_amdgcn_mfma_f32_16x16x32_bf16(ap, bv, o[ot], 0, 0, 0);
      }
    }
  }

  float inv[4];
#pragma unroll
  for (int r = 0; r < 4; ++r) inv[r] = (lsum[r] > 0.f) ? 1.f / lsum[r] : 0.f;
#pragma unroll
  for (int ot = 0; ot < 4; ++ot)
#pragma unroll
    for (int r = 0; r < 4; ++r) {
      const int rowg = q0 + (w << 4) + (lg << 2) + r;
      const int col = hoff + (ot << 4) + lm;
      ctx[((size_t)rowg << 10) + col] = f2b(o[ot][r] * inv[r]);
    }
}

// ---------------------------------------------------------------------------
// Dual LayerNorm: x = LN(a + res; g1,b1); xln = LN(x; gf,bf). Block per row.
// a/xo/xlo are ws bf16; res and params dtype via flag.
// ---------------------------------------------------------------------------
__global__ __launch_bounds__(256)
void ln_dual(const u16* __restrict__ a, const void* __restrict__ res, long roff,
             const void* __restrict__ g1, const void* __restrict__ b1,
             const void* __restrict__ gf, const void* __restrict__ bf,
             u16* __restrict__ xo, u16* __restrict__ xlo, const int* f_p) {
  __shared__ float red[8];
  const bool f = (*f_p != 0);
  const int row = blockIdx.x, t = threadIdx.x;
  const int lane = t & 63, w = t >> 6;
  const size_t base = (size_t)row << 10;
  const int c = t << 2;

  ushx4 a4 = *(const ushx4*)(a + base + c);
  float rv[4];
  ld4f(res, roff + (long)base + c, f, rv);
  float v[4], s = 0.f, ss = 0.f;
#pragma unroll
  for (int j = 0; j < 4; ++j) { v[j] = b2f(a4[j]) + rv[j]; s += v[j]; ss += v[j] * v[j]; }
#pragma unroll
  for (int off = 32; off > 0; off >>= 1) { s += __shfl_xor(s, off); ss += __shfl_xor(ss, off); }
  if (lane == 0) { red[w] = s; red[4 + w] = ss; }
  __syncthreads();
  s = red[0] + red[1] + red[2] + red[3];
  ss = red[4] + red[5] + red[6] + red[7];
  float mu = s * (1.f / 1024.f);
  float rstd = rsqrtf(fmaxf(ss * (1.f / 1024.f) - mu * mu, 0.f) + 1e-5f);

  float g4[4], b4[4];
  ld4f(g1, c, f, g4); ld4f(b1, c, f, b4);
  float x[4], s2 = 0.f, ss2 = 0.f;
  ushx4 xo4;
#pragma unroll
  for (int j = 0; j < 4; ++j) {
    x[j] = (v[j] - mu) * rstd * g4[j] + b4[j];
    xo4[j] = f2b(x[j]);
    s2 += x[j]; ss2 += x[j] * x[j];
  }
  *(ushx4*)(xo + base + c) = xo4;
#pragma unroll
  for (int off = 32; off > 0; off >>= 1) { s2 += __shfl_xor(s2, off); ss2 += __shfl_xor(ss2, off); }
  __syncthreads();
  if (lane == 0) { red[w] = s2; red[4 + w] = ss2; }
  __syncthreads();
  s2 = red[0] + red[1] + red[2] + red[3];
  ss2 = red[4] + red[5] + red[6] + red[7];
  float mu2 = s2 * (1.f / 1024.f);
  float rstd2 = rsqrtf(fmaxf(ss2 * (1.f / 1024.f) - mu2 * mu2, 0.f) + 1e-5f);

  ld4f(gf, c, f, g4); ld4f(bf, c, f, b4);
  ushx4 xl4;
#pragma unroll
  for (int j = 0; j < 4; ++j)
    xl4[j] = f2b((x[j] - mu2) * rstd2 * g4[j] + b4[j]);
  *(ushx4*)(xlo + base + c) = xl4;
}

// ---------------------------------------------------------------------------
// Final LayerNorm: out = LN(a + resx; g,b). Output dtype via flag.
// ---------------------------------------------------------------------------
__global__ __launch_bounds__(256)
void ln_final(const u16* __restrict__ a, const u16* __restrict__ resx,
              const void* __restrict__ g, const void* __restrict__ bb,
              void* __restrict__ out, long ooff, const int* f_p) {
  __shared__ float red[8];
  const bool f = (*f_p != 0);
  const int row = blockIdx.x, t = threadIdx.x;
  const int lane = t & 63, w = t >> 6;
  const size_t base = (size_t)row << 10;
  const int c = t << 2;

  ushx4 a4 = *(const ushx4*)(a + base + c);
  ushx4 r4 = *(const ushx4*)(resx + base + c);
  float v[4], s = 0.f, ss = 0.f;
#pragma unroll
  for (int j = 0; j < 4; ++j) { v[j] = b2f(a4[j]) + b2f(r4[j]); s += v[j]; ss += v[j] * v[j]; }
#pragma unroll
  for (int off = 32; off > 0; off >>= 1) { s += __shfl_xor(s, off); ss += __shfl_xor(ss, off); }
  if (lane == 0) { red[w] = s; red[4 + w] = ss; }
  __syncthreads();
  s = red[0] + red[1] + red[2] + red[3];
  ss = red[4] + red[5] + red[6] + red[7];
  float mu = s * (1.f / 1024.f);
  float rstd = rsqrtf(fmaxf(ss * (1.f / 1024.f) - mu * mu, 0.f) + 1e-5f);

  float g4[4], b4[4];
  ld4f(g, c, f, g4); ld4f(bb, c, f, b4);
  if (f) {
    fx4 o4;
#pragma unroll
    for (int j = 0; j < 4; ++j) o4[j] = (v[j] - mu) * rstd * g4[j] + b4[j];
    *(fx4*)((float*)out + ooff + base + c) = o4;
  } else {
    ushx4 o4;
#pragma unroll
    for (int j = 0; j < 4; ++j) o4[j] = f2b((v[j] - mu) * rstd * g4[j] + b4[j]);
    *(ushx4*)((u16*)out + ooff + base + c) = o4;
  }
}

// ---------------------------------------------------------------------------
extern "C" void kernel_launch(void* const* d_in, const int* in_sizes, int n_in,
                              void* d_out, int out_size, void* d_ws, size_t ws_size,
                              hipStream_t stream) {
  (void)in_sizes; (void)n_in; (void)out_size;
  const void* query = d_in[0];
  const void* keyi  = d_in[1];
  const void* value = d_in[2];
  const int*  mask  = (const int*)d_in[3];
  const void* Wq = d_in[4];
  const void* Wk = d_in[5];
  const void* Wv = d_in[6];
  const void* Wo = d_in[7];
  const void* bo = d_in[8];
  const void* g1 = d_in[9];
  const void* b1 = d_in[10];
  const void* g2 = d_in[11];
  const void* b2 = d_in[12];
  const void* gff = d_in[13];
  const void* bff = d_in[14];
  const void* W1 = d_in[15];
  const void* bf1 = d_in[16];
  const void* W2 = d_in[17];
  const void* bf2 = d_in[18];

  char* p = (char*)d_ws;
  int* flags = (int*)p;
  const int* F = flags;       // isf32 (input dtype)
  const int* Z = flags + 1;   // constant 0 (ws tensors are bf16)

  // Schedule selection by workspace size.
  const bool flat = ws_size >= (size_t)106 * 1024 * 1024;
  const int CH = flat ? 8192 : 2048;   // rows per chunk
  const int FH = flat ? 2048 : 1024;   // rows per FF sub-chunk
  const int nch = 8192 / CH;

  const size_t h0 = 4096;
  u16* W1T = (u16*)(p + h0);                       // [DFF, DM] 8MiB
  u16* W2T = W1T + (size_t)DFF * DM;               // [DM, DFF] 8MiB
  u16* hb  = (u16*)(p + h0 + ((size_t)16 << 20));  // FH x DFF bf16
  const size_t HB = (size_t)FH * DFF * 2;
  u16* r0 = (u16*)(p + h0 + ((size_t)16 << 20) + HB);
  const size_t CE = (size_t)CH * DM;               // elements per chunk buffer
  u16* qp = r0;            // -> x
  u16* kp = qp + CE;       // -> xln
  u16* vp = kp + CE;       // -> attn_out
  u16* ctxb = vp + CE;     // -> ff
  u16* x = qp; u16* xln = kp; u16* ao = vp; u16* ff = ctxb;

  dim3 blk(256);

  detect_kernel<<<1, 64, 0, stream>>>(query, flags);

  transpose_any<<<dim3(DFF / 64, DM / 64), blk, 0, stream>>>(W1, W1T, DM, DFF, F);
  transpose_any<<<dim3(DM / 64, DFF / 64), blk, 0, stream>>>(W2, W2T, DFF, DM, F);

  for (int c = 0; c < nch; ++c) {
    const long off = (long)c * CH * DM;
    dim3 gq((CH / 128) * (DM / 128));

    gemm_nt<false, false><<<gq, blk, 0, stream>>>(query, off, Wq, Wq, qp, CH, DM, DM, F, F, Z);
    gemm_nt<false, false><<<gq, blk, 0, stream>>>(keyi,  off, Wk, Wk, kp, CH, DM, DM, F, F, Z);
    gemm_nt<false, false><<<gq, blk, 0, stream>>>(value, off, Wv, Wv, vp, CH, DM, DM, F, F, Z);

    const int bpc = CH / SEQ, b0 = c * bpc;
    for (int bl = 0; bl < bpc; ++bl) {
      const size_t lo = (size_t)bl * SEQ * DM;
      attn_kernel<<<dim3(512), blk, 0, stream>>>(
          qp + lo, kp + lo, vp + lo,
          mask + (size_t)(b0 + bl) * SEQ * SEQ, ctxb + lo);
    }

    gemm_nt<false, true><<<gq, blk, 0, stream>>>(ctxb, 0, Wo, bo, ao, CH, DM, DM, Z, F, F);

    ln_dual<<<dim3(CH), blk, 0, stream>>>(ao, query, off, g1, b1, gff, bff, x, xln, F);

    for (int qs = 0; qs < CH / FH; ++qs) {
      const long so = (long)qs * FH * DM;
      gemm_nt<true, true><<<dim3((FH / 128) * (DFF / 128)), blk, 0, stream>>>(
          xln + so, 0, W1T, bf1, hb, FH, DFF, DM, Z, Z, F);
      gemm_nt<false, true><<<dim3((FH / 128) * (DM / 128)), blk, 0, stream>>>(
          hb, 0, W2T, bf2, ff + so, FH, DM, DFF, Z, Z, F);
    }

    ln_final<<<dim3(CH), blk, 0, stream>>>(ff, x, g2, b2, d_out, off, F);
  }
}

// Round 4
// 904.934 us; speedup vs baseline: 2.0539x; 2.0539x over previous
//
#include <hip/hip_runtime.h>

// ---------------------------------------------------------------------------
// SublayerConnection: MHA + residual/LN + FF + residual/LN
// B=4 S=2048 D=1024 H=16 Dk=64 Dff=4096.
// Round 4: ws-adaptive. New path (ws>=52MB): one-time bf16 weight packing +
// per-chunk input conversion, pure-bf16 DMA-staged GEMMs (global_load_lds 16B),
// QKV co-dispatched via grid.y=3, FF at full chunk M. Legacy path = round-3
// proven code (flag-based GEMMs) for small ws.
// ---------------------------------------------------------------------------

#define DM   1024
#define DFF  4096
#define SEQ  2048

typedef unsigned short u16;
typedef short          sx8  __attribute__((ext_vector_type(8)));
typedef unsigned short ushx8 __attribute__((ext_vector_type(8)));
typedef unsigned short ushx4 __attribute__((ext_vector_type(4)));
typedef float          fx4  __attribute__((ext_vector_type(4)));

__device__ __forceinline__ void async16(const void* g, void* l) {
  __builtin_amdgcn_global_load_lds((__attribute__((address_space(1))) void*)g,
                                   (__attribute__((address_space(3))) void*)l,
                                   16, 0, 0);
}
__device__ __forceinline__ float b2f(u16 u) {
  union { unsigned int i; float f; } v; v.i = ((unsigned int)u) << 16; return v.f;
}
__device__ __forceinline__ u16 f2b(float f) {
  union { float f; unsigned int i; } v; v.f = f;
  unsigned int r = v.i + 0x7fffu + ((v.i >> 16) & 1u);
  return (u16)(r >> 16);
}
__device__ __forceinline__ ushx8 ld8(const void* p, long idx, bool f32) {
  if (f32) {
    const float* s = (const float*)p + idx;
    fx4 a = *(const fx4*)s, b = *(const fx4*)(s + 4);
    ushx8 r;
    r[0] = f2b(a[0]); r[1] = f2b(a[1]); r[2] = f2b(a[2]); r[3] = f2b(a[3]);
    r[4] = f2b(b[0]); r[5] = f2b(b[1]); r[6] = f2b(b[2]); r[7] = f2b(b[3]);
    return r;
  }
  return *(const ushx8*)((const u16*)p + idx);
}
__device__ __forceinline__ void ld4f(const void* p, long idx, bool f32, float* o) {
  if (f32) {
    fx4 a = *(const fx4*)((const float*)p + idx);
    o[0] = a[0]; o[1] = a[1]; o[2] = a[2]; o[3] = a[3];
  } else {
    ushx4 a = *(const ushx4*)((const u16*)p + idx);
    o[0] = b2f(a[0]); o[1] = b2f(a[1]); o[2] = b2f(a[2]); o[3] = b2f(a[3]);
  }
}

// ---------------------------------------------------------------------------
__global__ void detect_kernel(const void* q, int* flags) {
  int lane = threadIdx.x;
  u16 v = ((const u16*)q)[lane << 1];
  int e = (v >> 7) & 0xff;
  int pl = (e >= 0x60 && e <= 0x8c) ? 1 : 0;
  unsigned long long m = __ballot(pl);
  if (lane == 0) { flags[0] = (__popcll(m) >= 40) ? 0 : 1; flags[1] = 0; }
}

// Pack Wq/Wk/Wv -> Wqkv [3*1024,1024] bf16 and Wo -> bf16.
__global__ __launch_bounds__(256)
void pack_w(const void* Wq, const void* Wk, const void* Wv, const void* Wo,
            u16* Wqkv, u16* Wo_bf, const int* f_p) {
  const bool f = (*f_p != 0);
  long i = (((long)blockIdx.x << 8) + threadIdx.x) << 3;
  const long QKVN = (long)3 * DM * DM;
  if (i < QKVN) {
    int row = (int)(i >> 10);
    const void* src = (row < DM) ? Wq : (row < 2 * DM ? Wk : Wv);
    long s = ((long)(row & (DM - 1)) << 10) + (i & 1023);
    *(ushx8*)(Wqkv + i) = ld8(src, s, f);
  } else {
    long j = i - QKVN;
    *(ushx8*)(Wo_bf + j) = ld8(Wo, j, f);
  }
}

// Elementwise convert n elems of src(+off) to bf16.
__global__ __launch_bounds__(256)
void conv_bf(const void* src, long off, u16* dst, long n, const int* f_p) {
  const bool f = (*f_p != 0);
  long i = (((long)blockIdx.x << 8) + threadIdx.x) << 3;
  if (i < n) *(ushx8*)(dst + i) = ld8(src, off + i, f);
}

// ---------------------------------------------------------------------------
// Pure-bf16 NT GEMM with global_load_lds(16B) staging. C=A@B^T (+bias)(+relu).
// grid.y = z selects (A,B,C) via element strides az/bz/cz. C row stride ldc.
// ---------------------------------------------------------------------------
template<bool RELU, bool BIAS>
__global__ __launch_bounds__(256)
void gemm_bb(const u16* __restrict__ A, long az, const u16* __restrict__ B, long bz,
             const void* __restrict__ bias, u16* __restrict__ C, long cz,
             int M, int N, int K, int ldc, const int* biasf_p) {
  __shared__ __align__(16) u16 sA[128 * 64];
  __shared__ __align__(16) u16 sB[128 * 64];
  const int z = blockIdx.y;
  A += (long)z * az; B += (long)z * bz; C += (long)z * cz;
  const bool biasf = BIAS && (*biasf_p != 0);
  const int t = threadIdx.x;
  const int lane = t & 63, w = t >> 6;
  const int lm = lane & 15, lg = lane >> 4;
  const int ntil = N >> 7;
  const int m0 = (blockIdx.x / ntil) << 7;
  const int n0 = (blockIdx.x % ntil) << 7;
  const int wm = (w & 1) << 6, wn = (w >> 1) << 6;

  fx4 acc[4][4];
#pragma unroll
  for (int i = 0; i < 4; ++i)
#pragma unroll
    for (int j = 0; j < 4; ++j) acc[i][j] = (fx4){0.f, 0.f, 0.f, 0.f};

  for (int kt = 0; kt < K; kt += 64) {
    __syncthreads();
#pragma unroll
    for (int it = 0; it < 4; ++it) {
      int ci = (it << 8) + t;
      int r = ci >> 3, cs = (ci & 7) ^ (r & 7);
      async16(&A[(size_t)(m0 + r) * K + kt + (cs << 3)], &sA[ci << 3]);
    }
#pragma unroll
    for (int it = 0; it < 4; ++it) {
      int ci = (it << 8) + t;
      int r = ci >> 3, cs = (ci & 7) ^ (r & 7);
      async16(&B[(size_t)(n0 + r) * K + kt + (cs << 3)], &sB[ci << 3]);
    }
    __syncthreads();
#pragma unroll
    for (int s = 0; s < 2; ++s) {
      const int g = (s << 2) + lg;
      sx8 afr[4], bfr[4];
#pragma unroll
      for (int i = 0; i < 4; ++i) {
        int ra = wm + (i << 4) + lm;
        afr[i] = *(const sx8*)&sA[ra * 64 + ((g ^ (ra & 7)) << 3)];
        int rb = wn + (i << 4) + lm;
        bfr[i] = *(const sx8*)&sB[rb * 64 + ((g ^ (rb & 7)) << 3)];
      }
#pragma unroll
      for (int i = 0; i < 4; ++i)
#pragma unroll
        for (int j = 0; j < 4; ++j)
          acc[i][j] = __builtin_amdgcn_mfma_f32_16x16x32_bf16(afr[i], bfr[j], acc[i][j], 0, 0, 0);
    }
  }

#pragma unroll
  for (int j = 0; j < 4; ++j) {
    const int col = n0 + wn + (j << 4) + lm;
    float bv = 0.f;
    if (BIAS) bv = biasf ? ((const float*)bias)[col] : b2f(((const u16*)bias)[col]);
#pragma unroll
    for (int i = 0; i < 4; ++i) {
      const int row0 = m0 + wm + (i << 4) + (lg << 2);
#pragma unroll
      for (int r = 0; r < 4; ++r) {
        float v = acc[i][j][r] + bv;
        if (RELU) v = fmaxf(v, 0.f);
        C[(size_t)(row0 + r) * ldc + col] = f2b(v);
      }
    }
  }
}

// ---------------------------------------------------------------------------
// Flag-dtype NT GEMM (legacy path, proven in round 3).
// ---------------------------------------------------------------------------
template<bool RELU, bool BIAS>
__global__ __launch_bounds__(256)
void gemm_nt(const void* __restrict__ A, long aoff, const void* __restrict__ Bm,
             const void* __restrict__ bias, u16* __restrict__ C,
             int M, int N, int K,
             const int* af_p, const int* bf_p, const int* biasf_p) {
  __shared__ __align__(16) u16 sA[128 * 64];
  __shared__ __align__(16) u16 sB[128 * 64];
  const bool af = (*af_p != 0), bfl = (*bf_p != 0), biasf = (*biasf_p != 0);
  const int t = threadIdx.x;
  const int lane = t & 63, w = t >> 6;
  const int lm = lane & 15, lg = lane >> 4;
  const int ntil = N >> 7;
  const int m0 = (blockIdx.x / ntil) << 7;
  const int n0 = (blockIdx.x % ntil) << 7;
  const int wm = (w & 1) << 6, wn = (w >> 1) << 6;

  fx4 acc[4][4];
#pragma unroll
  for (int i = 0; i < 4; ++i)
#pragma unroll
    for (int j = 0; j < 4; ++j) acc[i][j] = (fx4){0.f, 0.f, 0.f, 0.f};

  for (int kt = 0; kt < K; kt += 64) {
    __syncthreads();
#pragma unroll
    for (int it = 0; it < 4; ++it) {
      int ci = (it << 8) + t;
      int r = ci >> 3, cs = (ci & 7) ^ (r & 7);
      ushx8 va = ld8(A, aoff + (long)(m0 + r) * K + kt + (cs << 3), af);
      *(ushx8*)&sA[ci << 3] = va;
      ushx8 vb = ld8(Bm, (long)(n0 + r) * K + kt + (cs << 3), bfl);
      *(ushx8*)&sB[ci << 3] = vb;
    }
    __syncthreads();
#pragma unroll
    for (int s = 0; s < 2; ++s) {
      const int g = (s << 2) + lg;
      sx8 afr[4], bfr[4];
#pragma unroll
      for (int i = 0; i < 4; ++i) {
        int ra = wm + (i << 4) + lm;
        afr[i] = *(const sx8*)&sA[ra * 64 + ((g ^ (ra & 7)) << 3)];
        int rb = wn + (i << 4) + lm;
        bfr[i] = *(const sx8*)&sB[rb * 64 + ((g ^ (rb & 7)) << 3)];
      }
#pragma unroll
      for (int i = 0; i < 4; ++i)
#pragma unroll
        for (int j = 0; j < 4; ++j)
          acc[i][j] = __builtin_amdgcn_mfma_f32_16x16x32_bf16(afr[i], bfr[j], acc[i][j], 0, 0, 0);
    }
  }

#pragma unroll
  for (int j = 0; j < 4; ++j) {
    const int col = n0 + wn + (j << 4) + lm;
    float bv = 0.f;
    if (BIAS) bv = biasf ? ((const float*)bias)[col] : b2f(((const u16*)bias)[col]);
#pragma unroll
    for (int i = 0; i < 4; ++i) {
      const int row0 = m0 + wm + (i << 4) + (lg << 2);
#pragma unroll
      for (int r = 0; r < 4; ++r) {
        float v = acc[i][j][r] + bv;
        if (RELU) v = fmaxf(v, 0.f);
        C[(size_t)(row0 + r) * N + col] = f2b(v);
      }
    }
  }
}

// ---------------------------------------------------------------------------
__global__ __launch_bounds__(256)
void transpose_any(const void* __restrict__ in, u16* __restrict__ out,
                   int R, int C, const int* f_p) {
  __shared__ u16 tile[64][68];
  const bool f = (*f_p != 0);
  const int r0 = blockIdx.y << 6, c0 = blockIdx.x << 6;
  const int t = threadIdx.x;
#pragma unroll
  for (int it = 0; it < 4; ++it) {
    int j = (it << 8) + t;
    int rr = j >> 4, cc4 = (j & 15) << 2;
    float v[4];
    ld4f(in, (long)(r0 + rr) * C + c0 + cc4, f, v);
#pragma unroll
    for (int q = 0; q < 4; ++q) tile[rr][cc4 + q] = f2b(v[q]);
  }
  __syncthreads();
#pragma unroll
  for (int it = 0; it < 4; ++it) {
    int j = (it << 8) + t;
    int cc = j >> 4, rr4 = (j & 15) << 2;
    ushx4 v;
    v[0] = tile[rr4 + 0][cc]; v[1] = tile[rr4 + 1][cc];
    v[2] = tile[rr4 + 2][cc]; v[3] = tile[rr4 + 3][cc];
    *(ushx4*)&out[(size_t)(c0 + cc) * R + r0 + rr4] = v;
  }
}

// ---------------------------------------------------------------------------
// Flash attention over ONE batch. q/k/v pointers + row stride (1024 or 3072).
// Block = (h, 64 q rows); grid 512. 4 waves x 16 q rows.
// ---------------------------------------------------------------------------
__global__ __launch_bounds__(256)
void attn_kernel(const u16* __restrict__ qp, const u16* __restrict__ kp,
                 const u16* __restrict__ vp, int lds_,
                 const int* __restrict__ mask, u16* __restrict__ ctx) {
  __shared__ __align__(16) u16 sQ[64 * 64];
  __shared__ __align__(16) u16 sK[128 * 64];
  __shared__ __align__(16) u16 sVt[64 * 136];
  __shared__ __align__(16) u16 sP[4][16 * 136];

  const int id = blockIdx.x;
  const int q0 = (id & 31) << 6;
  const int h  = id >> 5;
  const int t = threadIdx.x, lane = t & 63, w = t >> 6;
  const int hoff = h << 6;
  const int lm = lane & 15, lg = lane >> 4;

#pragma unroll
  for (int it = 0; it < 2; ++it) {
    int ci = (it << 8) + t;
    int r = ci >> 3, cs = (ci & 7) ^ (r & 7);
    ushx8 v = *(const ushx8*)&qp[(size_t)(q0 + r) * lds_ + hoff + (cs << 3)];
    *(ushx8*)&sQ[ci << 3] = v;
  }

  fx4 o[4];
  float m_prev[4], lsum[4];
#pragma unroll
  for (int i = 0; i < 4; ++i) { o[i] = (fx4){0.f, 0.f, 0.f, 0.f}; m_prev[i] = -1e30f; lsum[i] = 0.f; }

  for (int kt = 0; kt < 16; ++kt) {
    const int k0 = kt << 7;
    __syncthreads();
#pragma unroll
    for (int it = 0; it < 4; ++it) {
      int ci = (it << 8) + t;
      int r = ci >> 3, cs = (ci & 7) ^ (r & 7);
      ushx8 v = *(const ushx8*)&kp[(size_t)(k0 + r) * lds_ + hoff + (cs << 3)];
      *(ushx8*)&sK[ci << 3] = v;
    }
    {
      const int key = t >> 1;
#pragma unroll
      for (int it = 0; it < 4; ++it) {
        int dc = (t & 1) + (it << 1);
        ushx8 vv = *(const ushx8*)&vp[(size_t)(k0 + key) * lds_ + hoff + (dc << 3)];
#pragma unroll
        for (int j = 0; j < 8; ++j)
          sVt[((dc << 3) + j) * 136 + key] = vv[j];
      }
    }
    __syncthreads();

    fx4 sc[8];
#pragma unroll
    for (int nt = 0; nt < 8; ++nt) sc[nt] = (fx4){0.f, 0.f, 0.f, 0.f};
#pragma unroll
    for (int s = 0; s < 2; ++s) {
      const int g = (s << 2) + lg;
      const int rowq = (w << 4) + lm;
      sx8 aq = *(const sx8*)&sQ[rowq * 64 + ((g ^ (rowq & 7)) << 3)];
#pragma unroll
      for (int nt = 0; nt < 8; ++nt) {
        int rk = (nt << 4) + lm;
        sx8 bk = *(const sx8*)&sK[rk * 64 + ((g ^ (rk & 7)) << 3)];
        sc[nt] = __builtin_amdgcn_mfma_f32_16x16x32_bf16(aq, bk, sc[nt], 0, 0, 0);
      }
    }

    float pmat[8][4];
    float tmax[4] = {-1e30f, -1e30f, -1e30f, -1e30f};
#pragma unroll
    for (int nt = 0; nt < 8; ++nt) {
      const int col = k0 + (nt << 4) + lm;
#pragma unroll
      for (int r = 0; r < 4; ++r) {
        const int rowg = q0 + (w << 4) + (lg << 2) + r;
        float v = sc[nt][r] * 0.125f;
        if (mask[((size_t)rowg << 11) + col] == 0) v = -1e9f;
        pmat[nt][r] = v;
        tmax[r] = fmaxf(tmax[r], v);
      }
    }
#pragma unroll
    for (int r = 0; r < 4; ++r)
#pragma unroll
      for (int off = 1; off < 16; off <<= 1)
        tmax[r] = fmaxf(tmax[r], __shfl_xor(tmax[r], off));

    float alpha[4], rsum[4] = {0.f, 0.f, 0.f, 0.f};
#pragma unroll
    for (int r = 0; r < 4; ++r) {
      float mn = fmaxf(m_prev[r], tmax[r]);
      alpha[r] = __expf(m_prev[r] - mn);
      m_prev[r] = mn;
    }
#pragma unroll
    for (int nt = 0; nt < 8; ++nt)
#pragma unroll
      for (int r = 0; r < 4; ++r) {
        float pv = __expf(pmat[nt][r] - m_prev[r]);
        pmat[nt][r] = pv;
        rsum[r] += pv;
      }
#pragma unroll
    for (int r = 0; r < 4; ++r) {
#pragma unroll
      for (int off = 1; off < 16; off <<= 1)
        rsum[r] += __shfl_xor(rsum[r], off);
      lsum[r] = lsum[r] * alpha[r] + rsum[r];
    }
#pragma unroll
    for (int ot = 0; ot < 4; ++ot)
#pragma unroll
      for (int r = 0; r < 4; ++r)
        o[ot][r] *= alpha[r];

    u16* pw = &sP[w][0];
#pragma unroll
    for (int nt = 0; nt < 8; ++nt)
#pragma unroll
      for (int r = 0; r < 4; ++r)
        pw[((lg << 2) + r) * 136 + (nt << 4) + lm] = f2b(pmat[nt][r]);

#pragma unroll
    for (int ks = 0; ks < 4; ++ks) {
      sx8 ap = *(const sx8*)&pw[lm * 136 + (ks << 5) + (lg << 3)];
#pragma unroll
      for (int ot = 0; ot < 4; ++ot) {
        int d = (ot << 4) + lm;
        sx8 bv = *(const sx8*)&sVt[d * 136 + (ks << 5) + (lg << 3)];
        o[ot] = __builtin_amdgcn_mfma_f32_16x16x32_bf16(ap, bv, o[ot], 0, 0, 0);
      }
    }
  }

  float inv[4];
#pragma unroll
  for (int r = 0; r < 4; ++r) inv[r] = (lsum[r] > 0.f) ? 1.f / lsum[r] : 0.f;
#pragma unroll
  for (int ot = 0; ot < 4; ++ot)
#pragma unroll
    for (int r = 0; r < 4; ++r) {
      const int rowg = q0 + (w << 4) + (lg << 2) + r;
      const int col = hoff + (ot << 4) + lm;
      ctx[((size_t)rowg << 10) + col] = f2b(o[ot][r] * inv[r]);
    }
}

// ---------------------------------------------------------------------------
__global__ __launch_bounds__(256)
void ln_dual(const u16* __restrict__ a, const void* __restrict__ res, long roff,
             const void* __restrict__ g1, const void* __restrict__ b1,
             const void* __restrict__ gf, const void* __restrict__ bf,
             u16* __restrict__ xo, u16* __restrict__ xlo, const int* f_p) {
  __shared__ float red[8];
  const bool f = (*f_p != 0);
  const int row = blockIdx.x, t = threadIdx.x;
  const int lane = t & 63, w = t >> 6;
  const size_t base = (size_t)row << 10;
  const int c = t << 2;

  ushx4 a4 = *(const ushx4*)(a + base + c);
  float rv[4];
  ld4f(res, roff + (long)base + c, f, rv);
  float v[4], s = 0.f, ss = 0.f;
#pragma unroll
  for (int j = 0; j < 4; ++j) { v[j] = b2f(a4[j]) + rv[j]; s += v[j]; ss += v[j] * v[j]; }
#pragma unroll
  for (int off = 32; off > 0; off >>= 1) { s += __shfl_xor(s, off); ss += __shfl_xor(ss, off); }
  if (lane == 0) { red[w] = s; red[4 + w] = ss; }
  __syncthreads();
  s = red[0] + red[1] + red[2] + red[3];
  ss = red[4] + red[5] + red[6] + red[7];
  float mu = s * (1.f / 1024.f);
  float rstd = rsqrtf(fmaxf(ss * (1.f / 1024.f) - mu * mu, 0.f) + 1e-5f);

  float g4[4], b4[4];
  ld4f(g1, c, f, g4); ld4f(b1, c, f, b4);
  float x[4], s2 = 0.f, ss2 = 0.f;
  ushx4 xo4;
#pragma unroll
  for (int j = 0; j < 4; ++j) {
    x[j] = (v[j] - mu) * rstd * g4[j] + b4[j];
    xo4[j] = f2b(x[j]);
    s2 += x[j]; ss2 += x[j] * x[j];
  }
  *(ushx4*)(xo + base + c) = xo4;
#pragma unroll
  for (int off = 32; off > 0; off >>= 1) { s2 += __shfl_xor(s2, off); ss2 += __shfl_xor(ss2, off); }
  __syncthreads();
  if (lane == 0) { red[w] = s2; red[4 + w] = ss2; }
  __syncthreads();
  s2 = red[0] + red[1] + red[2] + red[3];
  ss2 = red[4] + red[5] + red[6] + red[7];
  float mu2 = s2 * (1.f / 1024.f);
  float rstd2 = rsqrtf(fmaxf(ss2 * (1.f / 1024.f) - mu2 * mu2, 0.f) + 1e-5f);

  ld4f(gf, c, f, g4); ld4f(bf, c, f, b4);
  ushx4 xl4;
#pragma unroll
  for (int j = 0; j < 4; ++j)
    xl4[j] = f2b((x[j] - mu2) * rstd2 * g4[j] + b4[j]);
  *(ushx4*)(xlo + base + c) = xl4;
}

// ---------------------------------------------------------------------------
__global__ __launch_bounds__(256)
void ln_final(const u16* __restrict__ a, const u16* __restrict__ resx,
              const void* __restrict__ g, const void* __restrict__ bb,
              void* __restrict__ out, long ooff, const int* f_p) {
  __shared__ float red[8];
  const bool f = (*f_p != 0);
  const int row = blockIdx.x, t = threadIdx.x;
  const int lane = t & 63, w = t >> 6;
  const size_t base = (size_t)row << 10;
  const int c = t << 2;

  ushx4 a4 = *(const ushx4*)(a + base + c);
  ushx4 r4 = *(const ushx4*)(resx + base + c);
  float v[4], s = 0.f, ss = 0.f;
#pragma unroll
  for (int j = 0; j < 4; ++j) { v[j] = b2f(a4[j]) + b2f(r4[j]); s += v[j]; ss += v[j] * v[j]; }
#pragma unroll
  for (int off = 32; off > 0; off >>= 1) { s += __shfl_xor(s, off); ss += __shfl_xor(ss, off); }
  if (lane == 0) { red[w] = s; red[4 + w] = ss; }
  __syncthreads();
  s = red[0] + red[1] + red[2] + red[3];
  ss = red[4] + red[5] + red[6] + red[7];
  float mu = s * (1.f / 1024.f);
  float rstd = rsqrtf(fmaxf(ss * (1.f / 1024.f) - mu * mu, 0.f) + 1e-5f);

  float g4[4], b4[4];
  ld4f(g, c, f, g4); ld4f(bb, c, f, b4);
  if (f) {
    fx4 o4;
#pragma unroll
    for (int j = 0; j < 4; ++j) o4[j] = (v[j] - mu) * rstd * g4[j] + b4[j];
    *(fx4*)((float*)out + ooff + base + c) = o4;
  } else {
    ushx4 o4;
#pragma unroll
    for (int j = 0; j < 4; ++j) o4[j] = f2b((v[j] - mu) * rstd * g4[j] + b4[j]);
    *(ushx4*)((u16*)out + ooff + base + c) = o4;
  }
}

// ---------------------------------------------------------------------------
extern "C" void kernel_launch(void* const* d_in, const int* in_sizes, int n_in,
                              void* d_out, int out_size, void* d_ws, size_t ws_size,
                              hipStream_t stream) {
  (void)in_sizes; (void)n_in; (void)out_size;
  const void* query = d_in[0];
  const void* keyi  = d_in[1];
  const void* value = d_in[2];
  const int*  mask  = (const int*)d_in[3];
  const void* Wq = d_in[4];
  const void* Wk = d_in[5];
  const void* Wv = d_in[6];
  const void* Wo = d_in[7];
  const void* bo = d_in[8];
  const void* g1 = d_in[9];
  const void* b1 = d_in[10];
  const void* g2 = d_in[11];
  const void* b2 = d_in[12];
  const void* gff = d_in[13];
  const void* bff = d_in[14];
  const void* W1 = d_in[15];
  const void* bf1 = d_in[16];
  const void* W2 = d_in[17];
  const void* bf2 = d_in[18];

  char* p = (char*)d_ws;
  int* flags = (int*)p;
  const int* F = flags;
  const int* Z = flags + 1;
  dim3 blk(256);

  // footprint(CH) = 4096 + 24MiB (packed weights) + 7*CH*2048 bytes
  const size_t FIXED = 4096 + ((size_t)24 << 20);
  const size_t needA = FIXED + (size_t)4096 * 14336;   // ~80.0 MB
  const size_t needB = FIXED + (size_t)2048 * 14336;   // ~52.0 MB

  if (ws_size >= needB) {
    // ------------------------- NEW PATH -------------------------
    const int CH = (ws_size >= needA) ? 4096 : 2048;
    const int nch = 8192 / CH;

    u16* Wqkv  = (u16*)(p + 4096);                       // [3*1024,1024]
    u16* Wo_bf = Wqkv + (size_t)3 * DM * DM;             // [1024,1024]
    u16* W1T   = Wo_bf + (size_t)DM * DM;                // [4096,1024]
    u16* W2T   = W1T + (size_t)DFF * DM;                 // [1024,4096]
    u16* D0    = W2T + (size_t)DM * DFF;                 // in_bf / h
    u16* D1    = D0 + (size_t)3 * CH * DM;               // qkv / ao,x,xln
    u16* D2    = D1 + (size_t)3 * CH * DM;               // ctx / ff
    u16* qb = D0, *kb = D0 + (size_t)CH * DM, *vb = D0 + (size_t)2 * CH * DM;
    u16* qkv = D1;
    u16* ao = D1, *x = D1 + (size_t)CH * DM, *xln = D1 + (size_t)2 * CH * DM;
    u16* h = D0;                                         // CH*4096 elems
    u16* ctx = D2, *ff = D2;

    detect_kernel<<<1, 64, 0, stream>>>(query, flags);
    pack_w<<<dim3(2048), blk, 0, stream>>>(Wq, Wk, Wv, Wo, Wqkv, Wo_bf, F);
    transpose_any<<<dim3(DFF / 64, DM / 64), blk, 0, stream>>>(W1, W1T, DM, DFF, F);
    transpose_any<<<dim3(DM / 64, DFF / 64), blk, 0, stream>>>(W2, W2T, DFF, DM, F);

    for (int c = 0; c < nch; ++c) {
      const long off = (long)c * CH * DM;
      const long n = (long)CH * DM;
      conv_bf<<<dim3((int)(n >> 11)), blk, 0, stream>>>(query, off, qb, n, F);
      conv_bf<<<dim3((int)(n >> 11)), blk, 0, stream>>>(keyi,  off, kb, n, F);
      conv_bf<<<dim3((int)(n >> 11)), blk, 0, stream>>>(value, off, vb, n, F);

      // q/k/v projections co-dispatched: z in {0,1,2}
      gemm_bb<false, false><<<dim3((CH / 128) * 8, 3), blk, 0, stream>>>(
          qb, (long)CH * DM, Wqkv, (long)DM * DM, nullptr,
          qkv, 1024L, CH, DM, DM, 3072, Z);

      const int bpc = CH / SEQ, b0 = c * bpc;
      for (int bl = 0; bl < bpc; ++bl) {
        const size_t lo = (size_t)bl * SEQ;
        attn_kernel<<<dim3(512), blk, 0, stream>>>(
            qkv + lo * 3072, qkv + lo * 3072 + 1024, qkv + lo * 3072 + 2048, 3072,
            mask + (size_t)(b0 + bl) * SEQ * SEQ, ctx + lo * DM);
      }

      gemm_bb<false, true><<<dim3((CH / 128) * 8, 1), blk, 0, stream>>>(
          ctx, 0, Wo_bf, 0, bo, ao, 0, CH, DM, DM, DM, F);

      ln_dual<<<dim3(CH), blk, 0, stream>>>(ao, query, off, g1, b1, gff, bff, x, xln, F);

      gemm_bb<true, true><<<dim3((CH / 128) * 32, 1), blk, 0, stream>>>(
          xln, 0, W1T, 0, bf1, h, 0, CH, DFF, DM, DFF, F);
      gemm_bb<false, true><<<dim3((CH / 128) * 8, 1), blk, 0, stream>>>(
          h, 0, W2T, 0, bf2, ff, 0, CH, DM, DFF, DM, F);

      ln_final<<<dim3(CH), blk, 0, stream>>>(ff, x, g2, b2, d_out, off, F);
    }
  } else {
    // ------------------------- LEGACY PATH (round-3 proven) -------------------------
    const int CH = 2048, FH = 1024;
    const int nch = 8192 / CH;
    const size_t h0 = 4096;
    u16* W1T = (u16*)(p + h0);
    u16* W2T = W1T + (size_t)DFF * DM;
    u16* hb  = (u16*)(p + h0 + ((size_t)16 << 20));
    const size_t HB = (size_t)FH * DFF * 2;
    u16* r0 = (u16*)(p + h0 + ((size_t)16 << 20) + HB);
    const size_t CE = (size_t)CH * DM;
    u16* qp = r0;
    u16* kp = qp + CE;
    u16* vp = kp + CE;
    u16* ctxb = vp + CE;
    u16* x = qp; u16* xln = kp; u16* ao = vp; u16* ff = ctxb;

    detect_kernel<<<1, 64, 0, stream>>>(query, flags);
    transpose_any<<<dim3(DFF / 64, DM / 64), blk, 0, stream>>>(W1, W1T, DM, DFF, F);
    transpose_any<<<dim3(DM / 64, DFF / 64), blk, 0, stream>>>(W2, W2T, DFF, DM, F);

    for (int c = 0; c < nch; ++c) {
      const long off = (long)c * CH * DM;
      dim3 gq((CH / 128) * (DM / 128));

      gemm_nt<false, false><<<gq, blk, 0, stream>>>(query, off, Wq, Wq, qp, CH, DM, DM, F, F, Z);
      gemm_nt<false, false><<<gq, blk, 0, stream>>>(keyi,  off, Wk, Wk, kp, CH, DM, DM, F, F, Z);
      gemm_nt<false, false><<<gq, blk, 0, stream>>>(value, off, Wv, Wv, vp, CH, DM, DM, F, F, Z);

      const int bpc = CH / SEQ, b0 = c * bpc;
      for (int bl = 0; bl < bpc; ++bl) {
        const size_t lo = (size_t)bl * SEQ * DM;
        attn_kernel<<<dim3(512), blk, 0, stream>>>(
            qp + lo, kp + lo, vp + lo, 1024,
            mask + (size_t)(b0 + bl) * SEQ * SEQ, ctxb + lo);
      }

      gemm_nt<false, true><<<gq, blk, 0, stream>>>(ctxb, 0, Wo, bo, ao, CH, DM, DM, Z, F, F);

      ln_dual<<<dim3(CH), blk, 0, stream>>>(ao, query, off, g1, b1, gff, bff, x, xln, F);

      for (int qs = 0; qs < CH / FH; ++qs) {
        const long so = (long)qs * FH * DM;
        gemm_nt<true, true><<<dim3((FH / 128) * (DFF / 128)), blk, 0, stream>>>(
            xln + so, 0, W1T, bf1, hb, FH, DFF, DM, Z, Z, F);
        gemm_nt<false, true><<<dim3((FH / 128) * (DM / 128)), blk, 0, stream>>>(
            hb, 0, W2T, bf2, ff + so, FH, DM, DFF, Z, Z, F);
      }

      ln_final<<<dim3(CH), blk, 0, stream>>>(ff, x, g2, b2, d_out, off, F);
    }
  }
}